// Round 6
// baseline (152.808 us; speedup 1.0000x reference)
//
#include <hip/hip_runtime.h>
#include <math.h>

#define NB   16      // batch
#define NM   4096    // preds per image
#define NT   512     // targets per image
#define CAP  16      // max candidates per row (overflow -> exact fallback)
#define IOU_THR 0.1f
#define EPSG 1e-7f
#define NROWS (NB*NM)
#define T_AUC 512            // threads per auction block (== NT)
#define RPT   (NM / T_AUC)   // 8 rows per thread, strided ownership
#define CAPL  16384          // LDS candidate-store slots per image
#define SWEEPS 8             // chaotic sweeps per flag round

// row status
#define ST_UNRES   0
#define ST_HOLD    2
#define ST_MATCHED 3
#define ST_INVALID 4
#define ST_OVF     5

// ---------------------------------------------------------------------------
// Kernel 1: thread-per-row candidate build. Targets staged in LDS once per
// block (256 rows/block, no image straddle since 256 | 4096). Candidates
// stored transposed (e-major) for coalesced consumption.
// ---------------------------------------------------------------------------
__global__ __launch_bounds__(256) void cand_kernel(
    const float4* __restrict__ pred, const float4* __restrict__ tgt,
    int* __restrict__ counts, float2* __restrict__ cands)
{
    __shared__ float4 t_lds[NT];
    const int row = blockIdx.x * 256 + threadIdx.x;   // global row
    const int b   = row >> 12;                        // NM = 4096
    for (int i = threadIdx.x; i < NT; i += 256)
        t_lds[i] = tgt[b * NT + i];
    __syncthreads();

    float4 p = pred[row];
    float area_p = (p.z - p.x) * (p.w - p.y);
    int cnt = 0;
    #pragma unroll 4
    for (int j = 0; j < NT; ++j) {
        float4 t = t_lds[j];                          // wave-uniform: broadcast
        float area_t = (t.z - t.x) * (t.w - t.y);
        float w = fmaxf(fminf(p.z, t.z) - fmaxf(p.x, t.x), 0.f);
        float h = fmaxf(fminf(p.w, t.w) - fmaxf(p.y, t.y), 0.f);
        float inter = w * h;
        float uni   = (area_p + area_t) - inter;      // same association as ref
        float iou   = inter / uni;
        if (iou > IOU_THR) {
            if (cnt < CAP)
                cands[(size_t)cnt * NROWS + row] = make_float2(iou, __int_as_float(j));
            ++cnt;
        }
    }
    counts[row] = cnt;   // raw count; > CAP flags overflow
}

// ---------------------------------------------------------------------------
// Kernel 2: global auction to fixed point, one block (512 thr) per image.
// Candidates packed into LDS (CSR via block prefix-sum); chaotic multi-sweep
// rounds under a 3-barrier flag protocol. claim[j] = min row ever proposing j
// (monotone decreasing) -> unique fixed point == serial greedy.
// ---------------------------------------------------------------------------
__global__ __launch_bounds__(T_AUC) void auction_kernel(
    const float4* __restrict__ pred, const float4* __restrict__ tgt,
    const int* __restrict__ counts, const float2* __restrict__ cands,
    float* __restrict__ per_img)
{
    __shared__ float4   t_lds[NT];                 // 8 KB
    __shared__ unsigned claim[NT];                 // 2 KB
    __shared__ float          ciou_s[CAPL + CAP];  // 64 KB (+pad)
    __shared__ unsigned short cj_s[CAPL + CAP];    // 32 KB (+pad)
    __shared__ int wsum[T_AUC / 64], wbase[T_AUC / 64];
    __shared__ int flag, ovf_min, ovf_res;
    __shared__ float4 ovf_pred;
    __shared__ float rls[T_AUC / 64], rcs[T_AUC / 64], rvv[T_AUC / 64];
    __shared__ int   rjj[T_AUC / 64];

    const int b = blockIdx.x;
    const int t = threadIdx.x;
    const int gbase = b * NM;
    const int wv = t >> 6, lane = t & 63;

    t_lds[t] = tgt[b * NT + t];
    claim[t] = 0xFFFFFFFFu;

    // per-row state (all k-indexing static via unroll)
    int cn[RPT], cl[RPT], st[RPT], mj[RPT], ofs[RPT];
    int local = 0;
    #pragma unroll
    for (int k = 0; k < RPT; ++k) {
        int row = t + k * T_AUC;
        int c = counts[gbase + row];
        cn[k] = c;
        st[k] = (c == 0) ? ST_INVALID : (c > CAP ? ST_OVF : ST_UNRES);
        cl[k] = (c > 0 && c <= CAP) ? c : 0;
        mj[k] = -1;
        local += cl[k];
    }
    // block-wide exclusive prefix sum of cl -> LDS store offsets
    int incl = local;
    #pragma unroll
    for (int d = 1; d < 64; d <<= 1) {
        int n = __shfl_up(incl, d);
        if (lane >= d) incl += n;
    }
    int excl = incl - local;
    if (lane == 63) wsum[wv] = incl;
    __syncthreads();
    if (t == 0) {
        int run = 0;
        for (int w = 0; w < T_AUC / 64; ++w) { wbase[w] = run; run += wsum[w]; }
    }
    __syncthreads();
    int base = wbase[wv] + excl;
    #pragma unroll
    for (int k = 0; k < RPT; ++k) {
        ofs[k] = (cl[k] > 0 && base + cl[k] <= CAPL) ? base : -1;  // -1: global path
        base += cl[k];
    }
    // fill the LDS candidate store (reads coalesced per e-plane)
    #pragma unroll
    for (int k = 0; k < RPT; ++k) {
        if (ofs[k] >= 0) {
            int grow = gbase + t + k * T_AUC;
            for (int e = 0; e < cl[k]; ++e) {
                float2 c = cands[(size_t)e * NROWS + grow];
                ciou_s[ofs[k] + e] = c.x;
                cj_s[ofs[k] + e]   = (unsigned short)__float_as_int(c.y);
            }
        }
    }
    __syncthreads();

    while (true) {
        // ==== flag round: up to SWEEPS chaotic sweeps between barriers ====
        if (t == 0) flag = 0;
        __syncthreads();                           // A: reset visible
        bool did = false;
        for (int s = 0; s < SWEEPS; ++s) {
            bool act = false;
            #pragma unroll
            for (int k = 0; k < RPT; ++k) {
                unsigned row = (unsigned)(t + k * T_AUC);
                if (st[k] == ST_HOLD && claim[mj[k]] != row) st[k] = ST_UNRES;
                if (st[k] == ST_UNRES) {
                    act = true; did = true;
                    float bv = -1.f; int bj = -1;
                    if (ofs[k] >= 0) {
                        int o = ofs[k], c = cl[k];
                        #pragma unroll
                        for (int e = 0; e < CAP; ++e) {     // padded, branch-free
                            float vi = ciou_s[o + e];
                            int j = cj_s[o + e] & (NT - 1);
                            if (e < c && claim[j] >= row && vi > bv) { bv = vi; bj = j; }
                        }
                    } else {                                // capacity-overflow row
                        const float2* cp = cands + gbase + (int)row;
                        int c = cl[k];
                        #pragma unroll
                        for (int e = 0; e < CAP; ++e) {
                            float2 cc = make_float2(-1.f, 0.f);
                            if (e < c) cc = cp[(size_t)e * NROWS];
                            int j = __float_as_int(cc.y) & (NT - 1);
                            if (e < c && claim[j] >= row && cc.x > bv) { bv = cc.x; bj = j; }
                        }
                    }
                    if (bj < 0) st[k] = ST_INVALID;         // permanent (monotone)
                    else {
                        atomicMin(&claim[bj], row);
                        mj[k] = bj;
                        st[k] = (claim[bj] == row) ? ST_HOLD : ST_UNRES;
                    }
                }
            }
            if (!act) break;                                // locally idle
        }
        if (did) flag = 1;                                  // benign race: all write 1
        __syncthreads();                                    // B: sets visible
        int f = flag;
        __syncthreads();                                    // C: reads before next reset
        if (f) continue;                                    // not at fixed point yet

        // ==== overflow rows (count > CAP, ~never): exact serial fallback ====
        if (t == 0) ovf_min = 0x7FFFFFFF;
        __syncthreads();
        #pragma unroll
        for (int k = 0; k < RPT; ++k)
            if (st[k] == ST_OVF) atomicMin(&ovf_min, t + k * T_AUC);
        __syncthreads();
        const int rowF = ovf_min;                           // uniform
        if (rowF == 0x7FFFFFFF) break;                      // done
        #pragma unroll
        for (int k = 0; k < RPT; ++k)
            if (st[k] == ST_OVF && (t + k * T_AUC) == rowF)
                ovf_pred = pred[gbase + rowF];
        __syncthreads();
        {   // claim-aware argmax over all 512 targets (thread t = target t)
            float4 p4 = ovf_pred;
            float4 tt = t_lds[t];
            float area_p = (p4.z - p4.x) * (p4.w - p4.y);
            float area_t = (tt.z - tt.x) * (tt.w - tt.y);
            float w = fmaxf(fminf(p4.z, tt.z) - fmaxf(p4.x, tt.x), 0.f);
            float h = fmaxf(fminf(p4.w, tt.w) - fmaxf(p4.y, tt.y), 0.f);
            float inter = w * h;
            float iou = inter / ((area_p + area_t) - inter);
            bool freej = (claim[t] > (unsigned)rowF);
            float v = freej ? iou : -1.f;
            int bj = freej ? t : NT;
            #pragma unroll
            for (int off = 1; off < 64; off <<= 1) {
                float ov = __shfl_xor(v, off);
                int   oj = __shfl_xor(bj, off);
                if (ov > v || (ov == v && oj < bj)) { v = ov; bj = oj; }
            }
            if ((t & 63) == 0) { rvv[t >> 6] = v; rjj[t >> 6] = bj; }
        }
        __syncthreads();
        if (t == 0) {
            float v = rvv[0]; int bj = rjj[0];
            for (int w = 1; w < T_AUC / 64; ++w)
                if (rvv[w] > v || (rvv[w] == v && rjj[w] < bj)) { v = rvv[w]; bj = rjj[w]; }
            if (v > IOU_THR) { ovf_res = bj; claim[bj] = (unsigned)rowF; }   // steal
            else ovf_res = -1;
        }
        __syncthreads();
        #pragma unroll
        for (int k = 0; k < RPT; ++k)
            if (st[k] == ST_OVF && (t + k * T_AUC) == rowF) {
                mj[k] = ovf_res;
                st[k] = (ovf_res >= 0) ? ST_MATCHED : ST_INVALID;
            }
        // loop: auction re-runs; any displaced holder re-enters via snipe check
    }

    // ==== commit: GIoU for matched rows, deterministic reduction ====
    float ls = 0.f, cs = 0.f;
    #pragma unroll
    for (int k = 0; k < RPT; ++k) {
        if (st[k] == ST_HOLD || st[k] == ST_MATCHED) {
            int row = t + k * T_AUC;
            float4 p4 = pred[gbase + row];
            float4 tt = t_lds[mj[k]];
            float inter = fmaxf(fminf(p4.z, tt.z) - fmaxf(p4.x, tt.x), 0.f) *
                          fmaxf(fminf(p4.w, tt.w) - fmaxf(p4.y, tt.y), 0.f);
            float area_p = (p4.z - p4.x) * (p4.w - p4.y);
            float area_t = (tt.z - tt.x) * (tt.w - tt.y);
            float uni = area_p + area_t - inter;
            float iou = inter / (uni + EPSG);
            float enc = (fmaxf(p4.z, tt.z) - fminf(p4.x, tt.x)) *
                        (fmaxf(p4.w, tt.w) - fminf(p4.y, tt.y));
            float giou = iou - (enc - uni) / (enc + EPSG);
            ls += 1.f - giou;
            cs += 1.f;
        }
    }
    #pragma unroll
    for (int off = 32; off >= 1; off >>= 1) {
        ls += __shfl_xor(ls, off);
        cs += __shfl_xor(cs, off);
    }
    if ((t & 63) == 0) { rls[t >> 6] = ls; rcs[t >> 6] = cs; }
    __syncthreads();
    if (t == 0) {
        float L = 0.f, C = 0.f;
        for (int w = 0; w < T_AUC / 64; ++w) { L += rls[w]; C += rcs[w]; }
        per_img[b] = (C > 0.f) ? L / C : 0.f;
    }
}

// ---------------------------------------------------------------------------
// Kernel 3: mean over images -> scalar output. Deterministic (no atomics).
// ---------------------------------------------------------------------------
__global__ void reduce_kernel(const float* __restrict__ per_img,
                              float* __restrict__ out)
{
    if (threadIdx.x == 0 && blockIdx.x == 0) {
        float s = 0.f;
        for (int i = 0; i < NB; ++i) s += per_img[i];
        out[0] = s / (float)NB;
    }
}

extern "C" void kernel_launch(void* const* d_in, const int* in_sizes, int n_in,
                              void* d_out, int out_size, void* d_ws, size_t ws_size,
                              hipStream_t stream)
{
    const float4* pred = (const float4*)d_in[0];   // [16,4096,4] f32
    const float4* tgt  = (const float4*)d_in[1];   // [16,512,4]  f32

    char* ws = (char*)d_ws;
    // layout: counts [NROWS] i32 | cands [CAP*NROWS] float2 | per_img [NB] f32
    int*    counts  = (int*)ws;
    size_t  off1    = (size_t)NROWS * sizeof(int);                 // 256 KB
    float2* cands   = (float2*)(ws + off1);
    size_t  off2    = off1 + (size_t)CAP * NROWS * sizeof(float2); // +8 MB
    float*  per_img = (float*)(ws + off2);

    cand_kernel<<<NROWS / 256, 256, 0, stream>>>(pred, tgt, counts, cands);
    auction_kernel<<<NB, T_AUC, 0, stream>>>(pred, tgt, counts, cands, per_img);
    reduce_kernel<<<1, 64, 0, stream>>>(per_img, (float*)d_out);
}